// Round 7
// baseline (41.661 us; speedup 1.0000x reference)
//
#include <hip/hip_runtime.h>
#include <hip/hip_bf16.h>

// Tsit5 (Tsitouras 2011) coefficients
#define A21 0.161f
#define A31 (-0.008480655492356989f)
#define A32 0.335480655492357f
#define A41 2.8971530571054935f
#define A42 (-6.359448489975075f)
#define A43 4.3622954328695815f
#define A51 5.325864828439257f
#define A52 (-11.748883564062828f)
#define A53 7.4955393428898365f
#define A54 (-0.09249506636175525f)
#define A61 5.86145544294642f
#define A62 (-12.92096931784711f)
#define A63 8.159367898576159f
#define A64 (-0.071584973281401f)
#define A65 (-0.028269050394068383f)
#define B1 0.09646076681806523f
#define B2 0.01f
#define B3 0.4798896504144996f
#define B4 1.379008574103742f
#define B5 (-3.290069515436081f)
#define B6 2.324710524099774f

#define NORM 32768.0f
#define SUBSTEPS 8
#define IN_DIM 4096
#define OUT_DIM 1024

typedef float f32x4 __attribute__((ext_vector_type(4)));

// ---------------------------------------------------------------------------
// Kernel A (unchanged from R6): 4x4 downsample + Tsit5 per-group factor f^8.
// 1 px/thread, contiguous 16B/lane loads. Reads 64MB, writes 4MB to ws.
// High occupancy: loads need latency hiding.
// ---------------------------------------------------------------------------
__global__ __launch_bounds__(256) void ODERamp_downsample(
    const float* __restrict__ in,      // [4096, 4096]
    const int* __restrict__ ng_ptr,    // scalar ngroups
    float* __restrict__ f8_field)      // [1024*1024] in d_ws
{
    const int idx = blockIdx.x * blockDim.x + threadIdx.x;   // 0 .. 1M-1
    const int r = idx >> 10;
    const int c = idx & 1023;

    float s = 0.0f;
#pragma unroll
    for (int i = 0; i < 4; ++i) {
        const f32x4 v = *reinterpret_cast<const f32x4*>(
            in + (size_t)(4 * r + i) * IN_DIM + 4 * c);
        s += (v.x + v.y) + (v.z + v.w);
    }

    const int ngroups = *ng_ptr;
    const float dt = 1.0f / (float)(ngroups * SUBSTEPS);

    const float z  = s * (1.0f / NORM) * dt;
    const float q2 = 1.0f - A21 * z;
    const float q3 = 1.0f - z * (A31 + A32 * q2);
    const float q4 = 1.0f - z * (A41 + A42 * q2 + A43 * q3);
    const float q5 = 1.0f - z * (A51 + A52 * q2 + A53 * q3 + A54 * q4);
    const float q6 = 1.0f - z * (A61 + A62 * q2 + A63 * q3 + A64 * q4 + A65 * q5);
    const float R  = z * (B1 + B2 * q2 + B3 * q3 + B4 * q4 + B5 * q5 + B6 * q6);
    const float f  = 1.0f - R;
    const float f2 = f * f;
    const float f4 = f2 * f2;
    f8_field[idx] = f4 * f4;            // per-group factor f^8
}

// ---------------------------------------------------------------------------
// Kernel B (throttled): expansion with FILL-LIKE concurrency.
// 256 blocks x 256 thr = 1024 waves (~4/CU, like the 7.1TB/s fill's ~3/CU).
// Grid-stride over 4-px chunks; f32x4 stores (1KB/wave contiguous per plane).
// Theory: fewer concurrent write streams -> HBM row-buffer locality.
// ---------------------------------------------------------------------------
#define B_BLOCKS 256
#define B_THREADS 256

__global__ __launch_bounds__(B_THREADS) void ODERamp_expand(
    const float* __restrict__ f8_field, // [1024*1024] in d_ws
    const int* __restrict__ ng_ptr,
    float* __restrict__ out)            // [ngroups, 1024, 1024]
{
    const int tid = blockIdx.x * blockDim.x + threadIdx.x;   // 0 .. 65535
    const int n_thr = B_BLOCKS * B_THREADS;                  // 65536
    const int n_chunks = (OUT_DIM * OUT_DIM) / 4;            // 262144
    const int ngroups = *ng_ptr;
    const size_t plane4 = (size_t)(OUT_DIM * OUT_DIM) / 4;   // f32x4 stride

    for (int ch = tid; ch < n_chunks; ch += n_thr) {
        const int p = ch << 2;                               // base pixel
        const f32x4 f8 = *reinterpret_cast<const f32x4*>(f8_field + p);

        float a0 = 1.0f, a1 = 1.0f, a2 = 1.0f, a3 = 1.0f;   // (1-y) products
        f32x4* outp = reinterpret_cast<f32x4*>(out + p);
        for (int g = 0; g < ngroups; ++g) {
            a0 *= f8.x; a1 *= f8.y; a2 *= f8.z; a3 *= f8.w;
            f32x4 o;
            o.x = NORM - NORM * a0;
            o.y = NORM - NORM * a1;
            o.z = NORM - NORM * a2;
            o.w = NORM - NORM * a3;
            outp[(size_t)g * plane4] = o;
        }
    }
}

extern "C" void kernel_launch(void* const* d_in, const int* in_sizes, int n_in,
                              void* d_out, int out_size, void* d_ws, size_t ws_size,
                              hipStream_t stream) {
    const float* illum = (const float*)d_in[0];
    const int* ng = (const int*)d_in[1];
    float* out = (float*)d_out;
    float* f8_field = (float*)d_ws;              // 4MB scratch

    const int n_pix = OUT_DIM * OUT_DIM;         // 1,048,576
    const int block = 256;

    ODERamp_downsample<<<n_pix / block, block, 0, stream>>>(illum, ng, f8_field);
    ODERamp_expand<<<B_BLOCKS, B_THREADS, 0, stream>>>(f8_field, ng, out);
}

// Round 9
// 37.495 us; speedup vs baseline: 1.1111x; 1.1111x over previous
//
#include <hip/hip_runtime.h>
#include <hip/hip_bf16.h>

// Tsit5 (Tsitouras 2011) coefficients
#define A21 0.161f
#define A31 (-0.008480655492356989f)
#define A32 0.335480655492357f
#define A41 2.8971530571054935f
#define A42 (-6.359448489975075f)
#define A43 4.3622954328695815f
#define A51 5.325864828439257f
#define A52 (-11.748883564062828f)
#define A53 7.4955393428898365f
#define A54 (-0.09249506636175525f)
#define A61 5.86145544294642f
#define A62 (-12.92096931784711f)
#define A63 8.159367898576159f
#define A64 (-0.071584973281401f)
#define A65 (-0.028269050394068383f)
#define B1 0.09646076681806523f
#define B2 0.01f
#define B3 0.4798896504144996f
#define B4 1.379008574103742f
#define B5 (-3.290069515436081f)
#define B6 2.324710524099774f

#define NORM 32768.0f
#define SUBSTEPS 8
#define IN_DIM 4096
#define OUT_DIM 1024
#define PLANE (OUT_DIM * OUT_DIM)        // 1,048,576 px
#define PLANE4 (PLANE / 4)               // 262,144 f32x4 chunks (2^18)

typedef float f32x4 __attribute__((ext_vector_type(4)));

// ---------------------------------------------------------------------------
// Kernel A (unchanged): 4x4 downsample + Tsit5 per-group factor f^8.
// 1 px/thread, contiguous 16B/lane loads. Reads 64MB, writes 4MB to ws.
// ---------------------------------------------------------------------------
__global__ __launch_bounds__(256) void ODERamp_downsample(
    const float* __restrict__ in,      // [4096, 4096]
    const int* __restrict__ ng_ptr,    // scalar ngroups
    float* __restrict__ f8_field)      // [1024*1024] in d_ws
{
    const int idx = blockIdx.x * blockDim.x + threadIdx.x;   // 0 .. 1M-1
    const int r = idx >> 10;
    const int c = idx & 1023;

    float s = 0.0f;
#pragma unroll
    for (int i = 0; i < 4; ++i) {
        const f32x4 v = *reinterpret_cast<const f32x4*>(
            in + (size_t)(4 * r + i) * IN_DIM + 4 * c);
        s += (v.x + v.y) + (v.z + v.w);
    }

    const int ngroups = *ng_ptr;
    const float dt = 1.0f / (float)(ngroups * SUBSTEPS);

    const float z  = s * (1.0f / NORM) * dt;
    const float q2 = 1.0f - A21 * z;
    const float q3 = 1.0f - z * (A31 + A32 * q2);
    const float q4 = 1.0f - z * (A41 + A42 * q2 + A43 * q3);
    const float q5 = 1.0f - z * (A51 + A52 * q2 + A53 * q3 + A54 * q4);
    const float q6 = 1.0f - z * (A61 + A62 * q2 + A63 * q3 + A64 * q4 + A65 * q5);
    const float R  = z * (B1 + B2 * q2 + B3 * q3 + B4 * q4 + B5 * q5 + B6 * q6);
    const float f  = 1.0f - R;
    const float f2 = f * f;
    const float f4 = f2 * f2;
    f8_field[idx] = f4 * f4;            // per-group factor f^8
}

// ---------------------------------------------------------------------------
// Kernel B (plane-ordered): one thread per output f32x4 chunk, in FLAT
// output address order -> the write stream is a single linear march, exactly
// the pattern the 7.1 TB/s fill kernels use. Power f8^(g+1) computed
// directly via exp2f/log2f (single v_exp_f32/v_log_f32 on gfx950;
// f8 in [0.985,1] -> ~5e-3 abs output error, far under threshold).
// f8_field reads (4MB, x32 reuse) hit L2/L3.
// ---------------------------------------------------------------------------
__global__ __launch_bounds__(256) void ODERamp_expand(
    const float* __restrict__ f8_field, // [1024*1024] in d_ws
    float* __restrict__ out)            // [ngroups, 1024, 1024] flat
{
    const int q = blockIdx.x * blockDim.x + threadIdx.x;  // flat f32x4 index
    const int g = q >> 18;                                // plane (0..31)
    const int j = q & (PLANE4 - 1);                       // chunk in plane

    const f32x4 f8 = *reinterpret_cast<const f32x4*>(f8_field + (j << 2));
    const float k = (float)(g + 1);                       // f8^(g+1)

    f32x4 o;
    o.x = NORM - NORM * exp2f(k * log2f(f8.x));
    o.y = NORM - NORM * exp2f(k * log2f(f8.y));
    o.z = NORM - NORM * exp2f(k * log2f(f8.z));
    o.w = NORM - NORM * exp2f(k * log2f(f8.w));

    reinterpret_cast<f32x4*>(out)[q] = o;
}

extern "C" void kernel_launch(void* const* d_in, const int* in_sizes, int n_in,
                              void* d_out, int out_size, void* d_ws, size_t ws_size,
                              hipStream_t stream) {
    const float* illum = (const float*)d_in[0];
    const int* ng = (const int*)d_in[1];
    float* out = (float*)d_out;
    float* f8_field = (float*)d_ws;              // 4MB scratch

    const int block = 256;
    ODERamp_downsample<<<PLANE / block, block, 0, stream>>>(illum, ng, f8_field);

    // out_size = ngroups * PLANE floats; one thread per f32x4.
    const int n_chunks = out_size / 4;
    ODERamp_expand<<<n_chunks / block, block, 0, stream>>>(f8_field, out);
}